// Round 7
// baseline (304.517 us; speedup 1.0000x reference)
//
#include <hip/hip_runtime.h>
#include <hip/hip_bf16.h>

// (B,C,H,W) = (8,512,64,64)
constexpr int BATCH = 8;
constexpr int C = 512;
constexpr int HW = 4096;
constexpr long CN = (long)C * HW;   // 2,097,152
constexpr long CC = (long)C * C;    // 262,144

typedef __attribute__((ext_vector_type(8))) short short8;
typedef __attribute__((ext_vector_type(4))) short bf16x4;
typedef __attribute__((ext_vector_type(4))) float f32x4;

__device__ __forceinline__ void gload16(const void* g, void* l) {
  __builtin_amdgcn_global_load_lds(
      (const __attribute__((address_space(1))) void*)g,
      (__attribute__((address_space(3))) void*)l, 16, 0, 0);
}

__device__ __forceinline__ void hilo(float v, __hip_bfloat16& h, __hip_bfloat16& l) {
  h = __float2bfloat16(v);
  l = __float2bfloat16(v - __bfloat162float(h));
}
__device__ __forceinline__ short bfs(float v) {
  __hip_bfloat16 h = __float2bfloat16(v);
  return *(short*)&h;
}

// ---------------------------------------------------------------------------
// convx: X fp32 [C,HW] -> Xhi bf16 [C,HW]; Xt bf16 [HW,C].
// ---------------------------------------------------------------------------
__global__ __launch_bounds__(256) void convx_k(
    const float* __restrict__ x, __hip_bfloat16* __restrict__ xhi,
    __hip_bfloat16* __restrict__ xt) {
  const int b = blockIdx.z;
  const int n0 = blockIdx.x * 64, c0 = blockIdx.y * 64;
  const float* xb = x + (long)b * CN;
  __shared__ short t[64 * 65];
  const int tid = threadIdx.x;
#pragma unroll
  for (int it = 0; it < 2; ++it) {
    int slot = it * 256 + tid;
    int r = slot >> 3, cc = (slot & 7) * 8;
    const float* src = xb + (long)(c0 + r) * HW + n0 + cc;
    f32x4 v0 = *(const f32x4*)src, v1 = *(const f32x4*)(src + 4);
    short8 hh;
#pragma unroll
    for (int e = 0; e < 4; ++e) {
      hh[e] = bfs(v0[e]);
      hh[4 + e] = bfs(v1[e]);
    }
    long idx = (long)b * CN + (long)(c0 + r) * HW + n0 + cc;
    *(short8*)((short*)xhi + idx) = hh;
#pragma unroll
    for (int e = 0; e < 8; ++e) t[r * 65 + cc + e] = hh[e];
  }
  __syncthreads();
#pragma unroll
  for (int it = 0; it < 2; ++it) {
    int slot = it * 256 + tid;
    int r = slot >> 3, cc = (slot & 7) * 8;
    short8 o;
#pragma unroll
    for (int e = 0; e < 8; ++e) o[e] = t[(cc + e) * 65 + r];
    *(short8*)((short*)xt + (long)b * CN + (long)(n0 + r) * C + c0 + cc) = o;
  }
}

// ---------------------------------------------------------------------------
// Weight prep: z=0 w_phi->hi/lo; z=1 w_theta->hi/lo; z=2 w_g->transpose bf16;
// z=3 w_mask->bf16.
// ---------------------------------------------------------------------------
__global__ __launch_bounds__(256) void wprep_k(
    const float* __restrict__ wphi, const float* __restrict__ wtheta,
    const float* __restrict__ wg, const float* __restrict__ wmask,
    __hip_bfloat16* __restrict__ wph, __hip_bfloat16* __restrict__ wpl,
    __hip_bfloat16* __restrict__ wth, __hip_bfloat16* __restrict__ wtl,
    __hip_bfloat16* __restrict__ wgT, __hip_bfloat16* __restrict__ wm16) {
  const int z = blockIdx.z;
  const int r0 = blockIdx.y * 64, c0 = blockIdx.x * 64;
  const int tid = threadIdx.x;
  if (z == 2) {
    __shared__ __hip_bfloat16 t[64][65];
#pragma unroll
    for (int i = 0; i < 16; ++i) {
      int e = i * 256 + tid;
      int r = e >> 6, c = e & 63;
      t[r][c] = __float2bfloat16(wg[(long)(r0 + r) * C + c0 + c]);
    }
    __syncthreads();
#pragma unroll
    for (int i = 0; i < 16; ++i) {
      int e = i * 256 + tid;
      int r = e >> 6, c = e & 63;
      wgT[(long)(c0 + r) * C + r0 + c] = t[c][r];
    }
  } else {
#pragma unroll
    for (int i = 0; i < 16; ++i) {
      int e = i * 256 + tid;
      int r = e >> 6, c = e & 63;
      long idx = (long)(r0 + r) * C + c0 + c;
      if (z == 0) {
        __hip_bfloat16 h, l;
        hilo(wphi[idx], h, l);
        wph[idx] = h; wpl[idx] = l;
      } else if (z == 1) {
        __hip_bfloat16 h, l;
        hilo(wtheta[idx], h, l);
        wth[idx] = h; wtl[idx] = l;
      } else {
        wm16[idx] = __float2bfloat16(wmask[idx]);
      }
    }
  }
}

// ---------------------------------------------------------------------------
// Gram partials: plain bf16, 128x128 triangular tiles (10/batch), K-split 8.
// ---------------------------------------------------------------------------
__global__ __launch_bounds__(256) void gram_k(
    const __hip_bfloat16* __restrict__ xhi, float* __restrict__ gpart) {
  const int b = blockIdx.z;
  const int ks = blockIdx.y;
  int i = 0, rem = blockIdx.x;
  while (rem >= 4 - i) { rem -= 4 - i; ++i; }
  const int j = i + rem;
  const int m0 = i * 128, n0 = j * 128;

  const short* X = (const short*)(xhi + (long)b * CN);
  __shared__ short lds[2 * 128 * 32];
  const int tid = threadIdx.x, w = tid >> 6, lane = tid & 63;

  f32x4 acc[4][4] = {};
  const int wr = (w >> 1) * 64, wc = (w & 1) * 64;

  const int kbeg = ks * 512;
  for (int k0 = kbeg; k0 < kbeg + 512; k0 += 32) {
#pragma unroll
    for (int it = 0; it < 4; ++it) {
      int slot = (w & 1) * 256 + it * 64 + lane;
      int r = slot >> 2, p = slot & 3, c = p ^ ((r >> 1) & 3);
      int gr = (w < 2) ? (m0 + r) : (n0 + r);
      gload16(X + (long)gr * HW + k0 + c * 8, lds + ((w >> 1) * 512 + slot) * 8);
    }
    __syncthreads();
    short8 af[4], bfr[4];
    const int ch = lane >> 4;
#pragma unroll
    for (int mi = 0; mi < 4; ++mi) {
      int r = wr + mi * 16 + (lane & 15);
      af[mi] = *(const short8*)(lds + (r * 4 + (ch ^ ((r >> 1) & 3))) * 8);
    }
#pragma unroll
    for (int ni = 0; ni < 4; ++ni) {
      int r = wc + ni * 16 + (lane & 15);
      bfr[ni] = *(const short8*)(lds + 4096 + (r * 4 + (ch ^ ((r >> 1) & 3))) * 8);
    }
#pragma unroll
    for (int mi = 0; mi < 4; ++mi)
#pragma unroll
      for (int ni = 0; ni < 4; ++ni)
        acc[mi][ni] = __builtin_amdgcn_mfma_f32_16x16x32_bf16(af[mi], bfr[ni], acc[mi][ni], 0, 0, 0);
    __syncthreads();
  }

  float* P = gpart + ((((long)b * 10 + blockIdx.x) * 8 + ks) << 14);
#pragma unroll
  for (int mi = 0; mi < 4; ++mi)
#pragma unroll
    for (int ni = 0; ni < 4; ++ni)
#pragma unroll
      for (int rr = 0; rr < 4; ++rr) {
        int row = wr + mi * 16 + (lane >> 4) * 4 + rr;
        int col = wc + ni * 16 + (lane & 15);
        P[row * 128 + col] = acc[mi][ni][rr];
      }
}

// ---------------------------------------------------------------------------
// Gram reduce: sum 8 K-partials over a 64x128 half-tile, hi/lo split, write
// direct + LDS-transposed mirror. Grid (10, 2, 8).
// ---------------------------------------------------------------------------
__global__ __launch_bounds__(256) void gred_k(
    const float* __restrict__ gpart, __hip_bfloat16* __restrict__ gh,
    __hip_bfloat16* __restrict__ gl) {
  const int b = blockIdx.z;
  const int half = blockIdx.y;
  int i = 0, rem = blockIdx.x;
  while (rem >= 4 - i) { rem -= 4 - i; ++i; }
  const int j = i + rem;
  const int m0 = i * 128, n0 = j * 128;
  const float* P = gpart + (((long)b * 10 + blockIdx.x) << 17) + half * 8192;
  __shared__ float T[128][65];
  const int tid = threadIdx.x;
  const long dbase = (long)b * CC;

#pragma unroll
  for (int q = 0; q < 8; ++q) {
    int e = q * 1024 + tid * 4;
    int r = e >> 7, c = e & 127;
    f32x4 s = {};
#pragma unroll
    for (int ks = 0; ks < 8; ++ks) s += *(const f32x4*)(P + (ks << 14) + e);
    bf16x4 hh, ll;
#pragma unroll
    for (int u = 0; u < 4; ++u) {
      __hip_bfloat16 h, l;
      hilo(s[u], h, l);
      hh[u] = *(short*)&h;
      ll[u] = *(short*)&l;
      T[c + u][r] = s[u];
    }
    long idx = dbase + (long)(m0 + half * 64 + r) * 512 + n0 + c;
    *(bf16x4*)((short*)gh + idx) = hh;
    *(bf16x4*)((short*)gl + idx) = ll;
  }
  if (i != j) {
    __syncthreads();
#pragma unroll
    for (int q = 0; q < 8; ++q) {
      int e = q * 1024 + tid * 4;
      int rp = e >> 6, cp = e & 63;
      bf16x4 hh, ll;
#pragma unroll
      for (int u = 0; u < 4; ++u) {
        __hip_bfloat16 h, l;
        hilo(T[rp][cp + u], h, l);
        hh[u] = *(short*)&h;
        ll[u] = *(short*)&l;
      }
      long idx = dbase + (long)(n0 + rp) * 512 + m0 + half * 64 + cp;
      *(bf16x4*)((short*)gh + idx) = hh;
      *(bf16x4*)((short*)gl + idx) = ll;
    }
  }
}

// ---------------------------------------------------------------------------
// Small NT MFMA GEMM: C[512,512] = A[512,K=512] * B[512,K]^T, per batch.
// AH/BH: hi/lo split operands (3 MFMA passes). EPI 0: hi/lo out; 1: fp32; 2: bf16.
// ---------------------------------------------------------------------------
template <int AH, int BH, int EPI>
__global__ __launch_bounds__(256) void nt_small(
    const __hip_bfloat16* __restrict__ Ah_, const __hip_bfloat16* __restrict__ Al_,
    const __hip_bfloat16* __restrict__ Bh_, const __hip_bfloat16* __restrict__ Bl_,
    long aStr, long bStr, void* __restrict__ out1, void* __restrict__ out2) {
  const int b = blockIdx.z;
  const int m0 = blockIdx.y * 64, n0 = blockIdx.x * 64;
  const short* Ahp = (const short*)(Ah_ + (long)b * aStr);
  const short* Alp = AH ? (const short*)(Al_ + (long)b * aStr) : nullptr;
  const short* Bhp = (const short*)(Bh_ + (long)b * bStr);
  const short* Blp = BH ? (const short*)(Bl_ + (long)b * bStr) : nullptr;
  __shared__ short lds[4 * 64 * 64];
  const int tid = threadIdx.x, w = tid >> 6, lane = tid & 63;

  f32x4 acc[2][2] = {};
  const int wr = (w >> 1) * 32, wc = (w & 1) * 32;

  for (int k0 = 0; k0 < 512; k0 += 64) {
    if constexpr (AH && BH) {
      const short* src = (w == 0) ? Ahp : (w == 1) ? Alp : (w == 2) ? Bhp : Blp;
      const int rowbase = (w & 2) ? n0 : m0;
      short* lt = lds + w * 4096;
#pragma unroll
      for (int it = 0; it < 8; ++it) {
        int slot = it * 64 + lane;
        int r = slot >> 3, p = slot & 7, c = p ^ (r & 7);
        gload16(src + (long)(rowbase + r) * 512 + k0 + c * 8, lt + slot * 8);
      }
    } else {
      const short* src = (w < 2) ? Ahp : Bhp;
      const int rowbase = (w < 2) ? m0 : n0;
      short* lt = lds + (w >> 1) * 8192;
#pragma unroll
      for (int it = 0; it < 4; ++it) {
        int slot = (w & 1) * 256 + it * 64 + lane;
        int r = slot >> 3, p = slot & 7, c = p ^ (r & 7);
        gload16(src + (long)(rowbase + r) * 512 + k0 + c * 8, lt + slot * 8);
      }
    }
    __syncthreads();
#pragma unroll
    for (int kh = 0; kh < 2; ++kh) {
      short8 ah[2], al[2], bh[2], bl[2];
      const int ch = kh * 4 + (lane >> 4);
#pragma unroll
      for (int mi = 0; mi < 2; ++mi) {
        int r = wr + mi * 16 + (lane & 15);
        int off = (r * 8 + (ch ^ (r & 7))) * 8;
        ah[mi] = *(const short8*)(lds + off);
        if constexpr (AH) al[mi] = *(const short8*)(lds + 4096 + off);
      }
#pragma unroll
      for (int ni = 0; ni < 2; ++ni) {
        int r = wc + ni * 16 + (lane & 15);
        int off = (r * 8 + (ch ^ (r & 7))) * 8;
        bh[ni] = *(const short8*)(lds + 2 * 4096 + off);
        if constexpr (BH) bl[ni] = *(const short8*)(lds + 3 * 4096 + off);
      }
#pragma unroll
      for (int mi = 0; mi < 2; ++mi)
#pragma unroll
        for (int ni = 0; ni < 2; ++ni) {
          acc[mi][ni] = __builtin_amdgcn_mfma_f32_16x16x32_bf16(ah[mi], bh[ni], acc[mi][ni], 0, 0, 0);
          if constexpr (BH)
            acc[mi][ni] = __builtin_amdgcn_mfma_f32_16x16x32_bf16(ah[mi], bl[ni], acc[mi][ni], 0, 0, 0);
          if constexpr (AH)
            acc[mi][ni] = __builtin_amdgcn_mfma_f32_16x16x32_bf16(al[mi], bh[ni], acc[mi][ni], 0, 0, 0);
        }
    }
    __syncthreads();
  }

#pragma unroll
  for (int mi = 0; mi < 2; ++mi)
#pragma unroll
    for (int ni = 0; ni < 2; ++ni)
#pragma unroll
      for (int rr = 0; rr < 4; ++rr) {
        int row = m0 + wr + mi * 16 + (lane >> 4) * 4 + rr;
        int col = n0 + wc + ni * 16 + (lane & 15);
        long idx = (long)b * CC + (long)row * 512 + col;
        float v = acc[mi][ni][rr];
        if constexpr (EPI == 0) {
          __hip_bfloat16 h, l;
          hilo(v, h, l);
          ((__hip_bfloat16*)out1)[idx] = h;
          ((__hip_bfloat16*)out2)[idx] = l;
        } else if constexpr (EPI == 1) {
          ((float*)out1)[idx] = v;
        } else {
          ((__hip_bfloat16*)out1)[idx] = __float2bfloat16(v);
        }
      }
}

// ---------------------------------------------------------------------------
// Row softmax over 512 cols, fp32 in -> bf16 out.
// ---------------------------------------------------------------------------
__global__ __launch_bounds__(256) void softmax_k(const float* __restrict__ a,
                                                 __hip_bfloat16* __restrict__ o) {
  const float* row = a + (long)blockIdx.x * 512;
  __hip_bfloat16* orow = o + (long)blockIdx.x * 512;
  const int t = threadIdx.x;
  float v0 = row[t], v1 = row[t + 256];
  __shared__ float sm[256];
  sm[t] = fmaxf(v0, v1);
  __syncthreads();
  for (int s = 128; s > 0; s >>= 1) {
    if (t < s) sm[t] = fmaxf(sm[t], sm[t + s]);
    __syncthreads();
  }
  float mx = sm[0];
  __syncthreads();
  float e0 = expf(v0 - mx), e1 = expf(v1 - mx);
  sm[t] = e0 + e1;
  __syncthreads();
  for (int s = 128; s > 0; s >>= 1) {
    if (t < s) sm[t] += sm[t + s];
    __syncthreads();
  }
  float inv = 1.0f / sm[0];
  orow[t] = __float2bfloat16(e0 * inv);
  orow[t + 256] = __float2bfloat16(e1 * inv);
}

// ---------------------------------------------------------------------------
// Big NT MFMA GEMM, 128x128 tile, BK=32, M=512 N=4096 K=512.
// Flat grid (128,1,8) with m-inner decode: the 4 m-repeats of each B-tile are
// consecutive in dispatch order -> B re-reads hit L2.
// MODE 0: y = Mb (NT) Xt, permuted B-rows; epilogue through LDS -> short8
//         permuted stores (== torch permute+view, pre-transposed).
// MODE 1: out = gamma*(w_mask (NT) yvT) + x; epilogue through LDS in 32-row
//         chunks -> f32x4 x-reads / out-writes.
// ---------------------------------------------------------------------------
template <int MODE>
__global__ __launch_bounds__(256) void big_k(
    const __hip_bfloat16* __restrict__ Aw, const __hip_bfloat16* __restrict__ Bm,
    void* __restrict__ Cout, const float* __restrict__ x,
    const float* __restrict__ gammaPtr, long aStride) {
  const int b = blockIdx.z;
  const int lin = blockIdx.x;                // 0..127
  const int m0 = (lin & 3) * 128;
  const int n0 = (lin >> 2) * 128;
  const short* A = (const short*)(Aw + (long)b * aStride);
  const short* B = (const short*)(Bm + (long)b * CN);
  __shared__ short lds[12288];               // 24 KB: staging 16 KB / epilogues
  const int tid = threadIdx.x, w = tid >> 6, lane = tid & 63;

  f32x4 acc[4][4] = {};
  const int wr = (w >> 1) * 64, wc = (w & 1) * 64;

  for (int k0 = 0; k0 < 512; k0 += 32) {
#pragma unroll
    for (int i = 0; i < 4; ++i) {
      int slot = (w & 1) * 256 + i * 64 + lane;
      int r = slot >> 2, p = slot & 3, c = p ^ ((r >> 1) & 3);
      const short* src;
      long goff;
      if (w < 2) {
        src = A;
        goff = (long)(m0 + r) * 512 + k0 + c * 8;
      } else {
        int gr = (MODE == 0) ? (n0 + (r & 15) * 8 + (r >> 4)) : (n0 + r);
        src = B;
        goff = (long)gr * 512 + k0 + c * 8;
      }
      gload16(src + goff, lds + ((w >> 1) * 512 + slot) * 8);
    }
    __syncthreads();
    short8 af[4], bfr[4];
    const int ch = lane >> 4;
#pragma unroll
    for (int mi = 0; mi < 4; ++mi) {
      int r = wr + mi * 16 + (lane & 15);
      af[mi] = *(const short8*)(lds + (r * 4 + (ch ^ ((r >> 1) & 3))) * 8);
    }
#pragma unroll
    for (int ni = 0; ni < 4; ++ni) {
      int r = wc + ni * 16 + (lane & 15);
      bfr[ni] = *(const short8*)(lds + 4096 + (r * 4 + (ch ^ ((r >> 1) & 3))) * 8);
    }
#pragma unroll
    for (int mi = 0; mi < 4; ++mi)
#pragma unroll
      for (int ni = 0; ni < 4; ++ni)
        acc[mi][ni] = __builtin_amdgcn_mfma_f32_16x16x32_bf16(af[mi], bfr[ni], acc[mi][ni], 0, 0, 0);
    __syncthreads();
  }

  if (MODE == 0) {
    // LDS half-tile: [t(4)][row(128)][24 shorts (16 used, 48B rows for b128)]
    __hip_bfloat16* yv = (__hip_bfloat16*)Cout + (long)b * CN;
    const int u = lane & 15, quad = lane >> 4;
#pragma unroll
    for (int half = 0; half < 2; ++half) {
      if ((wc >> 4) == half * 4) {
#pragma unroll
        for (int ni = 0; ni < 4; ++ni)
#pragma unroll
          for (int mi = 0; mi < 4; ++mi)
#pragma unroll
            for (int r = 0; r < 4; ++r) {
              int row = wr + mi * 16 + quad * 4 + r;
              lds[ni * 3072 + row * 24 + u] = bfs(acc[mi][ni][r]);
            }
      }
      __syncthreads();
      // 512 rows x 32B; 2 lanes per row, 16B stores
#pragma unroll
      for (int it = 0; it < 4; ++it) {
        int slot = it * 256 + tid;           // 0..1023
        int rrow = slot >> 1, hl = slot & 1;
        int tl = rrow >> 7, mrow = rrow & 127;
        short8 vrow = *(const short8*)(lds + tl * 3072 + mrow * 24 + hl * 8);
        long gaddr = ((long)((half * 4 + tl) * 512 + m0 + mrow)) * 512 +
                     (n0 >> 3) + hl * 8;
        *(short8*)((short*)yv + gaddr) = vrow;
      }
      __syncthreads();
    }
  } else {
    // LDS chunk: [32 rows][132 floats] (16.5 KB), 4 chunks of 32 rows
    float* T = (float*)lds;
    float* outp = (float*)Cout + (long)b * CN;
    const float* xb = x + (long)b * CN;
    const float g0 = gammaPtr[0];
    const int u = lane & 15, quad = lane >> 4;
#pragma unroll
    for (int chk = 0; chk < 4; ++chk) {
      if ((wr >> 6) == (chk >> 1)) {
#pragma unroll
        for (int mi2 = 0; mi2 < 2; ++mi2) {
          int mi = (chk & 1) * 2 + mi2;
#pragma unroll
          for (int ni = 0; ni < 4; ++ni)
#pragma unroll
            for (int r = 0; r < 4; ++r) {
              int lrow = (mi & 1) * 16 + quad * 4 + r;
              T[lrow * 132 + wc + ni * 16 + u] = acc[mi][ni][r];
            }
        }
      }
      __syncthreads();
      int rr_ = tid >> 3, cg = (tid & 7) * 16;
      long grow = (long)(m0 + chk * 32 + rr_) * HW + n0 + cg;
      const float* Trow = T + rr_ * 132 + cg;
#pragma unroll
      for (int q = 0; q < 4; ++q) {
        int qp = (q + rr_) & 3;              // bank de-conflict swizzle
        f32x4 av = *(const f32x4*)(Trow + qp * 4);
        f32x4 xv = *(const f32x4*)(xb + grow + qp * 4);
        f32x4 ov = g0 * av + xv;
        *(f32x4*)(outp + grow + qp * 4) = ov;
      }
      __syncthreads();
    }
  }
}

// ---------------------------------------------------------------------------
// Orchestration. Workspace ~127 MB.
// ---------------------------------------------------------------------------
extern "C" void kernel_launch(void* const* d_in, const int* in_sizes, int n_in,
                              void* d_out, int out_size, void* d_ws, size_t ws_size,
                              hipStream_t stream) {
  const float* x       = (const float*)d_in[0];
  const float* w_phi   = (const float*)d_in[1];
  const float* w_theta = (const float*)d_in[2];
  const float* w_g     = (const float*)d_in[3];
  const float* w_mask  = (const float*)d_in[4];
  const float* gamma   = (const float*)d_in[5];
  float* out = (float*)d_out;

  __hip_bfloat16* xhi = (__hip_bfloat16*)d_ws;
  __hip_bfloat16* xt  = xhi + BATCH * CN;
  __hip_bfloat16* gh  = xt + BATCH * CN;
  __hip_bfloat16* gl  = gh + BATCH * CC;
  __hip_bfloat16* t1h = gl + BATCH * CC;
  __hip_bfloat16* t1l = t1h + BATCH * CC;
  __hip_bfloat16* wph = t1l + BATCH * CC;
  __hip_bfloat16* wpl = wph + CC;
  __hip_bfloat16* wth = wpl + CC;
  __hip_bfloat16* wtl = wth + CC;
  __hip_bfloat16* wgT = wtl + CC;
  __hip_bfloat16* wm16 = wgT + CC;
  float* gpart = (float*)(wm16 + CC);     // 40 MB
  // aliases (stream-ordered lifetimes don't overlap):
  float* logits           = (float*)gh;
  __hip_bfloat16* attn16  = t1h;
  __hip_bfloat16* mb16    = t1l;
  __hip_bfloat16* yvT     = xhi;

  convx_k<<<dim3(64, 8, BATCH), 256, 0, stream>>>(x, xhi, xt);
  wprep_k<<<dim3(8, 8, 4), 256, 0, stream>>>(w_phi, w_theta, w_g, w_mask,
                                             wph, wpl, wth, wtl, wgT, wm16);
  gram_k<<<dim3(10, 8, BATCH), 256, 0, stream>>>(xhi, gpart);
  gred_k<<<dim3(10, 2, BATCH), 256, 0, stream>>>(gpart, gh, gl);
  nt_small<1, 1, 0><<<dim3(8, 8, BATCH), 256, 0, stream>>>(
      wph, wpl, gh, gl, 0, CC, t1h, t1l);
  nt_small<1, 1, 1><<<dim3(8, 8, BATCH), 256, 0, stream>>>(
      t1h, t1l, wth, wtl, CC, 0, logits, nullptr);
  softmax_k<<<dim3(BATCH * C), dim3(256), 0, stream>>>(logits, attn16);
  nt_small<0, 0, 2><<<dim3(8, 8, BATCH), 256, 0, stream>>>(
      attn16, nullptr, wgT, nullptr, CC, 0, mb16, nullptr);
  big_k<0><<<dim3(128, 1, BATCH), 256, 0, stream>>>(mb16, xt, yvT, nullptr, nullptr, CC);
  big_k<1><<<dim3(128, 1, BATCH), 256, 0, stream>>>(wm16, yvT, out, x, gamma, 0);
}

// Round 8
// 291.306 us; speedup vs baseline: 1.0453x; 1.0453x over previous
//
#include <hip/hip_runtime.h>
#include <hip/hip_bf16.h>

// (B,C,H,W) = (8,512,64,64)
constexpr int BATCH = 8;
constexpr int C = 512;
constexpr int HW = 4096;
constexpr long CN = (long)C * HW;   // 2,097,152
constexpr long CC = (long)C * C;    // 262,144

typedef __attribute__((ext_vector_type(8))) short short8;
typedef __attribute__((ext_vector_type(4))) short bf16x4;
typedef __attribute__((ext_vector_type(4))) float f32x4;

__device__ __forceinline__ void gload16(const void* g, void* l) {
  __builtin_amdgcn_global_load_lds(
      (const __attribute__((address_space(1))) void*)g,
      (__attribute__((address_space(3))) void*)l, 16, 0, 0);
}

__device__ __forceinline__ void hilo(float v, __hip_bfloat16& h, __hip_bfloat16& l) {
  h = __float2bfloat16(v);
  l = __float2bfloat16(v - __bfloat162float(h));
}
__device__ __forceinline__ short bfs(float v) {
  __hip_bfloat16 h = __float2bfloat16(v);
  return *(short*)&h;
}

// ---------------------------------------------------------------------------
// convx: X fp32 [C,HW] -> Xhi bf16 [C,HW]; Xt bf16 [HW,C].
// ---------------------------------------------------------------------------
__global__ __launch_bounds__(256) void convx_k(
    const float* __restrict__ x, __hip_bfloat16* __restrict__ xhi,
    __hip_bfloat16* __restrict__ xt) {
  const int b = blockIdx.z;
  const int n0 = blockIdx.x * 64, c0 = blockIdx.y * 64;
  const float* xb = x + (long)b * CN;
  __shared__ short t[64 * 65];
  const int tid = threadIdx.x;
#pragma unroll
  for (int it = 0; it < 2; ++it) {
    int slot = it * 256 + tid;
    int r = slot >> 3, cc = (slot & 7) * 8;
    const float* src = xb + (long)(c0 + r) * HW + n0 + cc;
    f32x4 v0 = *(const f32x4*)src, v1 = *(const f32x4*)(src + 4);
    short8 hh;
#pragma unroll
    for (int e = 0; e < 4; ++e) {
      hh[e] = bfs(v0[e]);
      hh[4 + e] = bfs(v1[e]);
    }
    long idx = (long)b * CN + (long)(c0 + r) * HW + n0 + cc;
    *(short8*)((short*)xhi + idx) = hh;
#pragma unroll
    for (int e = 0; e < 8; ++e) t[r * 65 + cc + e] = hh[e];
  }
  __syncthreads();
#pragma unroll
  for (int it = 0; it < 2; ++it) {
    int slot = it * 256 + tid;
    int r = slot >> 3, cc = (slot & 7) * 8;
    short8 o;
#pragma unroll
    for (int e = 0; e < 8; ++e) o[e] = t[(cc + e) * 65 + r];
    *(short8*)((short*)xt + (long)b * CN + (long)(n0 + r) * C + c0 + cc) = o;
  }
}

// ---------------------------------------------------------------------------
// Weight prep: z=0 w_phi->hi/lo; z=1 w_theta->hi/lo; z=2 w_g->transpose bf16;
// z=3 w_mask->bf16.
// ---------------------------------------------------------------------------
__global__ __launch_bounds__(256) void wprep_k(
    const float* __restrict__ wphi, const float* __restrict__ wtheta,
    const float* __restrict__ wg, const float* __restrict__ wmask,
    __hip_bfloat16* __restrict__ wph, __hip_bfloat16* __restrict__ wpl,
    __hip_bfloat16* __restrict__ wth, __hip_bfloat16* __restrict__ wtl,
    __hip_bfloat16* __restrict__ wgT, __hip_bfloat16* __restrict__ wm16) {
  const int z = blockIdx.z;
  const int r0 = blockIdx.y * 64, c0 = blockIdx.x * 64;
  const int tid = threadIdx.x;
  if (z == 2) {
    __shared__ __hip_bfloat16 t[64][65];
#pragma unroll
    for (int i = 0; i < 16; ++i) {
      int e = i * 256 + tid;
      int r = e >> 6, c = e & 63;
      t[r][c] = __float2bfloat16(wg[(long)(r0 + r) * C + c0 + c]);
    }
    __syncthreads();
#pragma unroll
    for (int i = 0; i < 16; ++i) {
      int e = i * 256 + tid;
      int r = e >> 6, c = e & 63;
      wgT[(long)(c0 + r) * C + r0 + c] = t[c][r];
    }
  } else {
#pragma unroll
    for (int i = 0; i < 16; ++i) {
      int e = i * 256 + tid;
      int r = e >> 6, c = e & 63;
      long idx = (long)(r0 + r) * C + c0 + c;
      if (z == 0) {
        __hip_bfloat16 h, l;
        hilo(wphi[idx], h, l);
        wph[idx] = h; wpl[idx] = l;
      } else if (z == 1) {
        __hip_bfloat16 h, l;
        hilo(wtheta[idx], h, l);
        wth[idx] = h; wtl[idx] = l;
      } else {
        wm16[idx] = __float2bfloat16(wmask[idx]);
      }
    }
  }
}

// ---------------------------------------------------------------------------
// Gram partials: plain bf16, 128x128 triangular tiles (10/batch), K-split 8.
// BK=64 (8 iters, 32 MFMA between barrier drains). LDS 32 KB.
// ---------------------------------------------------------------------------
__global__ __launch_bounds__(256) void gram_k(
    const __hip_bfloat16* __restrict__ xhi, float* __restrict__ gpart) {
  const int b = blockIdx.z;
  const int ks = blockIdx.y;
  int i = 0, rem = blockIdx.x;
  while (rem >= 4 - i) { rem -= 4 - i; ++i; }
  const int j = i + rem;
  const int m0 = i * 128, n0 = j * 128;

  const short* X = (const short*)(xhi + (long)b * CN);
  __shared__ short lds[2 * 128 * 64];      // 32 KB: A 128x64, B 128x64
  const int tid = threadIdx.x, w = tid >> 6, lane = tid & 63;

  f32x4 acc[4][4] = {};
  const int wr = (w >> 1) * 64, wc = (w & 1) * 64;

  const int kbeg = ks * 512;
  for (int k0 = kbeg; k0 < kbeg + 512; k0 += 64) {
    // waves 0,1 stage A rows (m0..), waves 2,3 stage B rows (n0..)
    // 128-row x 64-k tile = 1024 16B chunks per operand; swizzle c = p^(r&7)
#pragma unroll
    for (int it = 0; it < 8; ++it) {
      int slot = (w & 1) * 512 + it * 64 + lane;   // 0..1023
      int r = slot >> 3, p = slot & 7, c = p ^ (r & 7);
      int gr = (w < 2) ? (m0 + r) : (n0 + r);
      gload16(X + (long)gr * HW + k0 + c * 8, lds + ((w >> 1) * 1024 + slot) * 8);
    }
    __syncthreads();
#pragma unroll
    for (int kh = 0; kh < 2; ++kh) {
      short8 af[4], bfr[4];
      const int ch = kh * 4 + (lane >> 4);
#pragma unroll
      for (int mi = 0; mi < 4; ++mi) {
        int r = wr + mi * 16 + (lane & 15);
        af[mi] = *(const short8*)(lds + (r * 8 + (ch ^ (r & 7))) * 8);
      }
#pragma unroll
      for (int ni = 0; ni < 4; ++ni) {
        int r = wc + ni * 16 + (lane & 15);
        bfr[ni] = *(const short8*)(lds + 8192 + (r * 8 + (ch ^ (r & 7))) * 8);
      }
#pragma unroll
      for (int mi = 0; mi < 4; ++mi)
#pragma unroll
        for (int ni = 0; ni < 4; ++ni)
          acc[mi][ni] = __builtin_amdgcn_mfma_f32_16x16x32_bf16(af[mi], bfr[ni], acc[mi][ni], 0, 0, 0);
    }
    __syncthreads();
  }

  float* P = gpart + ((((long)b * 10 + blockIdx.x) * 8 + ks) << 14);
#pragma unroll
  for (int mi = 0; mi < 4; ++mi)
#pragma unroll
    for (int ni = 0; ni < 4; ++ni)
#pragma unroll
      for (int rr = 0; rr < 4; ++rr) {
        int row = wr + mi * 16 + (lane >> 4) * 4 + rr;
        int col = wc + ni * 16 + (lane & 15);
        P[row * 128 + col] = acc[mi][ni][rr];
      }
}

// ---------------------------------------------------------------------------
// Gram reduce: sum 8 K-partials over a 64x128 half-tile, hi/lo split, write
// direct + LDS-transposed mirror. Grid (10, 2, 8).
// ---------------------------------------------------------------------------
__global__ __launch_bounds__(256) void gred_k(
    const float* __restrict__ gpart, __hip_bfloat16* __restrict__ gh,
    __hip_bfloat16* __restrict__ gl) {
  const int b = blockIdx.z;
  const int half = blockIdx.y;
  int i = 0, rem = blockIdx.x;
  while (rem >= 4 - i) { rem -= 4 - i; ++i; }
  const int j = i + rem;
  const int m0 = i * 128, n0 = j * 128;
  const float* P = gpart + (((long)b * 10 + blockIdx.x) << 17) + half * 8192;
  __shared__ float T[128][65];
  const int tid = threadIdx.x;
  const long dbase = (long)b * CC;

#pragma unroll
  for (int q = 0; q < 8; ++q) {
    int e = q * 1024 + tid * 4;
    int r = e >> 7, c = e & 127;
    f32x4 s = {};
#pragma unroll
    for (int ks = 0; ks < 8; ++ks) s += *(const f32x4*)(P + (ks << 14) + e);
    bf16x4 hh, ll;
#pragma unroll
    for (int u = 0; u < 4; ++u) {
      __hip_bfloat16 h, l;
      hilo(s[u], h, l);
      hh[u] = *(short*)&h;
      ll[u] = *(short*)&l;
      T[c + u][r] = s[u];
    }
    long idx = dbase + (long)(m0 + half * 64 + r) * 512 + n0 + c;
    *(bf16x4*)((short*)gh + idx) = hh;
    *(bf16x4*)((short*)gl + idx) = ll;
  }
  if (i != j) {
    __syncthreads();
#pragma unroll
    for (int q = 0; q < 8; ++q) {
      int e = q * 1024 + tid * 4;
      int rp = e >> 6, cp = e & 63;
      bf16x4 hh, ll;
#pragma unroll
      for (int u = 0; u < 4; ++u) {
        __hip_bfloat16 h, l;
        hilo(T[rp][cp + u], h, l);
        hh[u] = *(short*)&h;
        ll[u] = *(short*)&l;
      }
      long idx = dbase + (long)(n0 + rp) * 512 + m0 + half * 64 + cp;
      *(bf16x4*)((short*)gh + idx) = hh;
      *(bf16x4*)((short*)gl + idx) = ll;
    }
  }
}

// ---------------------------------------------------------------------------
// Small NT MFMA GEMM: C[512,512] = A[512,K=512] * B[512,K]^T, per batch.
// AH/BH: hi/lo split operands (3 MFMA passes). EPI 0: hi/lo out; 1: fp32; 2: bf16.
// ---------------------------------------------------------------------------
template <int AH, int BH, int EPI>
__global__ __launch_bounds__(256) void nt_small(
    const __hip_bfloat16* __restrict__ Ah_, const __hip_bfloat16* __restrict__ Al_,
    const __hip_bfloat16* __restrict__ Bh_, const __hip_bfloat16* __restrict__ Bl_,
    long aStr, long bStr, void* __restrict__ out1, void* __restrict__ out2) {
  const int b = blockIdx.z;
  const int m0 = blockIdx.y * 64, n0 = blockIdx.x * 64;
  const short* Ahp = (const short*)(Ah_ + (long)b * aStr);
  const short* Alp = AH ? (const short*)(Al_ + (long)b * aStr) : nullptr;
  const short* Bhp = (const short*)(Bh_ + (long)b * bStr);
  const short* Blp = BH ? (const short*)(Bl_ + (long)b * bStr) : nullptr;
  __shared__ short lds[4 * 64 * 64];
  const int tid = threadIdx.x, w = tid >> 6, lane = tid & 63;

  f32x4 acc[2][2] = {};
  const int wr = (w >> 1) * 32, wc = (w & 1) * 32;

  for (int k0 = 0; k0 < 512; k0 += 64) {
    if constexpr (AH && BH) {
      const short* src = (w == 0) ? Ahp : (w == 1) ? Alp : (w == 2) ? Bhp : Blp;
      const int rowbase = (w & 2) ? n0 : m0;
      short* lt = lds + w * 4096;
#pragma unroll
      for (int it = 0; it < 8; ++it) {
        int slot = it * 64 + lane;
        int r = slot >> 3, p = slot & 7, c = p ^ (r & 7);
        gload16(src + (long)(rowbase + r) * 512 + k0 + c * 8, lt + slot * 8);
      }
    } else {
      const short* src = (w < 2) ? Ahp : Bhp;
      const int rowbase = (w < 2) ? m0 : n0;
      short* lt = lds + (w >> 1) * 8192;
#pragma unroll
      for (int it = 0; it < 4; ++it) {
        int slot = (w & 1) * 256 + it * 64 + lane;
        int r = slot >> 3, p = slot & 7, c = p ^ (r & 7);
        gload16(src + (long)(rowbase + r) * 512 + k0 + c * 8, lt + slot * 8);
      }
    }
    __syncthreads();
#pragma unroll
    for (int kh = 0; kh < 2; ++kh) {
      short8 ah[2], al[2], bh[2], bl[2];
      const int ch = kh * 4 + (lane >> 4);
#pragma unroll
      for (int mi = 0; mi < 2; ++mi) {
        int r = wr + mi * 16 + (lane & 15);
        int off = (r * 8 + (ch ^ (r & 7))) * 8;
        ah[mi] = *(const short8*)(lds + off);
        if constexpr (AH) al[mi] = *(const short8*)(lds + 4096 + off);
      }
#pragma unroll
      for (int ni = 0; ni < 2; ++ni) {
        int r = wc + ni * 16 + (lane & 15);
        int off = (r * 8 + (ch ^ (r & 7))) * 8;
        bh[ni] = *(const short8*)(lds + 2 * 4096 + off);
        if constexpr (BH) bl[ni] = *(const short8*)(lds + 3 * 4096 + off);
      }
#pragma unroll
      for (int mi = 0; mi < 2; ++mi)
#pragma unroll
        for (int ni = 0; ni < 2; ++ni) {
          acc[mi][ni] = __builtin_amdgcn_mfma_f32_16x16x32_bf16(ah[mi], bh[ni], acc[mi][ni], 0, 0, 0);
          if constexpr (BH)
            acc[mi][ni] = __builtin_amdgcn_mfma_f32_16x16x32_bf16(ah[mi], bl[ni], acc[mi][ni], 0, 0, 0);
          if constexpr (AH)
            acc[mi][ni] = __builtin_amdgcn_mfma_f32_16x16x32_bf16(al[mi], bh[ni], acc[mi][ni], 0, 0, 0);
        }
    }
    __syncthreads();
  }

#pragma unroll
  for (int mi = 0; mi < 2; ++mi)
#pragma unroll
    for (int ni = 0; ni < 2; ++ni)
#pragma unroll
      for (int rr = 0; rr < 4; ++rr) {
        int row = m0 + wr + mi * 16 + (lane >> 4) * 4 + rr;
        int col = n0 + wc + ni * 16 + (lane & 15);
        long idx = (long)b * CC + (long)row * 512 + col;
        float v = acc[mi][ni][rr];
        if constexpr (EPI == 0) {
          __hip_bfloat16 h, l;
          hilo(v, h, l);
          ((__hip_bfloat16*)out1)[idx] = h;
          ((__hip_bfloat16*)out2)[idx] = l;
        } else if constexpr (EPI == 1) {
          ((float*)out1)[idx] = v;
        } else {
          ((__hip_bfloat16*)out1)[idx] = __float2bfloat16(v);
        }
      }
}

// ---------------------------------------------------------------------------
// Row softmax over 512 cols, fp32 in -> bf16 out.
// ---------------------------------------------------------------------------
__global__ __launch_bounds__(256) void softmax_k(const float* __restrict__ a,
                                                 __hip_bfloat16* __restrict__ o) {
  const float* row = a + (long)blockIdx.x * 512;
  __hip_bfloat16* orow = o + (long)blockIdx.x * 512;
  const int t = threadIdx.x;
  float v0 = row[t], v1 = row[t + 256];
  __shared__ float sm[256];
  sm[t] = fmaxf(v0, v1);
  __syncthreads();
  for (int s = 128; s > 0; s >>= 1) {
    if (t < s) sm[t] = fmaxf(sm[t], sm[t + s]);
    __syncthreads();
  }
  float mx = sm[0];
  __syncthreads();
  float e0 = expf(v0 - mx), e1 = expf(v1 - mx);
  sm[t] = e0 + e1;
  __syncthreads();
  for (int s = 128; s > 0; s >>= 1) {
    if (t < s) sm[t] += sm[t + s];
    __syncthreads();
  }
  float inv = 1.0f / sm[0];
  orow[t] = __float2bfloat16(e0 * inv);
  orow[t + 256] = __float2bfloat16(e1 * inv);
}

// ---------------------------------------------------------------------------
// Big NT MFMA GEMM, 128x128 tile, BK=64 (8 iters), M=512 N=4096 K=512.
// Flat grid (128,1,8), m-inner decode (B-tile repeats adjacent in dispatch).
// Round-6 scalar epilogues (proven fastest; LDS-staged variant regressed).
// MODE 0: y = Mb (NT) Xt, permuted B-rows -> yvT bf16 (== permute+view).
// MODE 1: out = gamma*(w_mask (NT) yvT) + x, fp32 store.
// ---------------------------------------------------------------------------
template <int MODE>
__global__ __launch_bounds__(256) void big_k(
    const __hip_bfloat16* __restrict__ Aw, const __hip_bfloat16* __restrict__ Bm,
    void* __restrict__ Cout, const float* __restrict__ x,
    const float* __restrict__ gammaPtr, long aStride) {
  const int b = blockIdx.z;
  const int lin = blockIdx.x;                // 0..127
  const int m0 = (lin & 3) * 128;
  const int n0 = (lin >> 2) * 128;
  const short* A = (const short*)(Aw + (long)b * aStride);
  const short* B = (const short*)(Bm + (long)b * CN);
  __shared__ short lds[2 * 128 * 64];        // 32 KB: A 128x64, B 128x64
  const int tid = threadIdx.x, w = tid >> 6, lane = tid & 63;

  f32x4 acc[4][4] = {};
  const int wr = (w >> 1) * 64, wc = (w & 1) * 64;

  for (int k0 = 0; k0 < 512; k0 += 64) {
#pragma unroll
    for (int it = 0; it < 8; ++it) {
      int slot = (w & 1) * 512 + it * 64 + lane;   // 0..1023
      int r = slot >> 3, p = slot & 7, c = p ^ (r & 7);
      const short* src;
      long goff;
      if (w < 2) {
        src = A;
        goff = (long)(m0 + r) * 512 + k0 + c * 8;
      } else {
        int gr = (MODE == 0) ? (n0 + (r & 15) * 8 + (r >> 4)) : (n0 + r);
        src = B;
        goff = (long)gr * 512 + k0 + c * 8;
      }
      gload16(src + goff, lds + ((w >> 1) * 1024 + slot) * 8);
    }
    __syncthreads();
#pragma unroll
    for (int kh = 0; kh < 2; ++kh) {
      short8 af[4], bfr[4];
      const int ch = kh * 4 + (lane >> 4);
#pragma unroll
      for (int mi = 0; mi < 4; ++mi) {
        int r = wr + mi * 16 + (lane & 15);
        af[mi] = *(const short8*)(lds + (r * 8 + (ch ^ (r & 7))) * 8);
      }
#pragma unroll
      for (int ni = 0; ni < 4; ++ni) {
        int r = wc + ni * 16 + (lane & 15);
        bfr[ni] = *(const short8*)(lds + 8192 + (r * 8 + (ch ^ (r & 7))) * 8);
      }
#pragma unroll
      for (int mi = 0; mi < 4; ++mi)
#pragma unroll
        for (int ni = 0; ni < 4; ++ni)
          acc[mi][ni] = __builtin_amdgcn_mfma_f32_16x16x32_bf16(af[mi], bfr[ni], acc[mi][ni], 0, 0, 0);
    }
    __syncthreads();
  }

  if (MODE == 0) {
    __hip_bfloat16* yv = (__hip_bfloat16*)Cout + (long)b * CN;
    const int u = lane & 15;
#pragma unroll
    for (int mi = 0; mi < 4; ++mi)
#pragma unroll
      for (int ni = 0; ni < 4; ++ni) {
        int t = (wc >> 4) + ni;
        long base = ((long)(t * 512 + m0 + wr + mi * 16 + (lane >> 4) * 4)) * 512 +
                    (n0 >> 3) + u;
#pragma unroll
        for (int r = 0; r < 4; ++r)
          yv[base + (long)r * 512] = __float2bfloat16(acc[mi][ni][r]);
      }
  } else {
    float* outp = (float*)Cout + (long)b * CN;
    const float* xb = x + (long)b * CN;
    const float g0 = gammaPtr[0];
#pragma unroll
    for (int mi = 0; mi < 4; ++mi)
#pragma unroll
      for (int ni = 0; ni < 4; ++ni)
#pragma unroll
        for (int r = 0; r < 4; ++r) {
          long idx = (long)(m0 + wr + mi * 16 + (lane >> 4) * 4 + r) * HW +
                     n0 + wc + ni * 16 + (lane & 15);
          outp[idx] = g0 * acc[mi][ni][r] + xb[idx];
        }
  }
}

// ---------------------------------------------------------------------------
// Orchestration. Workspace ~127 MB.
// ---------------------------------------------------------------------------
extern "C" void kernel_launch(void* const* d_in, const int* in_sizes, int n_in,
                              void* d_out, int out_size, void* d_ws, size_t ws_size,
                              hipStream_t stream) {
  const float* x       = (const float*)d_in[0];
  const float* w_phi   = (const float*)d_in[1];
  const float* w_theta = (const float*)d_in[2];
  const float* w_g     = (const float*)d_in[3];
  const float* w_mask  = (const float*)d_in[4];
  const float* gamma   = (const float*)d_in[5];
  float* out = (float*)d_out;

  __hip_bfloat16* xhi = (__hip_bfloat16*)d_ws;
  __hip_bfloat16* xt  = xhi + BATCH * CN;
  __hip_bfloat16* gh  = xt + BATCH * CN;
  __hip_bfloat16* gl  = gh + BATCH * CC;
  __hip_bfloat16* t1h = gl + BATCH * CC;
  __hip_bfloat16* t1l = t1h + BATCH * CC;
  __hip_bfloat16* wph = t1l + BATCH * CC;
  __hip_bfloat16* wpl = wph + CC;
  __hip_bfloat16* wth = wpl + CC;
  __hip_bfloat16* wtl = wth + CC;
  __hip_bfloat16* wgT = wtl + CC;
  __hip_bfloat16* wm16 = wgT + CC;
  float* gpart = (float*)(wm16 + CC);     // 40 MB
  // aliases (stream-ordered lifetimes don't overlap):
  float* logits           = (float*)gh;
  __hip_bfloat16* attn16  = t1h;
  __hip_bfloat16* mb16    = t1l;
  __hip_bfloat16* yvT     = xhi;

  convx_k<<<dim3(64, 8, BATCH), 256, 0, stream>>>(x, xhi, xt);
  wprep_k<<<dim3(8, 8, 4), 256, 0, stream>>>(w_phi, w_theta, w_g, w_mask,
                                             wph, wpl, wth, wtl, wgT, wm16);
  gram_k<<<dim3(10, 8, BATCH), 256, 0, stream>>>(xhi, gpart);
  gred_k<<<dim3(10, 2, BATCH), 256, 0, stream>>>(gpart, gh, gl);
  nt_small<1, 1, 0><<<dim3(8, 8, BATCH), 256, 0, stream>>>(
      wph, wpl, gh, gl, 0, CC, t1h, t1l);
  nt_small<1, 1, 1><<<dim3(8, 8, BATCH), 256, 0, stream>>>(
      t1h, t1l, wth, wtl, CC, 0, logits, nullptr);
  softmax_k<<<dim3(BATCH * C), dim3(256), 0, stream>>>(logits, attn16);
  nt_small<0, 0, 2><<<dim3(8, 8, BATCH), 256, 0, stream>>>(
      attn16, nullptr, wgT, nullptr, CC, 0, mb16, nullptr);
  big_k<0><<<dim3(128, 1, BATCH), 256, 0, stream>>>(mb16, xt, yvT, nullptr, nullptr, CC);
  big_k<1><<<dim3(128, 1, BATCH), 256, 0, stream>>>(wm16, yvT, out, x, gamma, 0);
}